// Round 3
// baseline (195.193 us; speedup 1.0000x reference)
//
#include <hip/hip_runtime.h>
#include <hip/hip_bf16.h>
#include <stdint.h>

#define BROWS 4096
#define DDIM  1024

typedef __bf16 bf16_t;
typedef __bf16 bf16x8 __attribute__((ext_vector_type(8)));
typedef float  f32x4  __attribute__((ext_vector_type(4)));
typedef unsigned int u32;

#define GEMM_BLOCKS 1024   // (4096/128)^2 tiles
#define NKT 16             // K-tiles of BK=64

// Lb bit layout (ballot-native): word w = (j>>8)*4 + (j&3), bit b = (j&255)>>2.

__device__ __forceinline__ unsigned short f2bf_bits(float f) {
    union { float f; unsigned int u; } v; v.f = f;
    unsigned int u = v.u;
    unsigned int r = (u + 0x7fffu + ((u >> 16) & 1u)) >> 16;
    return (unsigned short)r;
}

__device__ __forceinline__ void gload16(const void* g, void* l) {
    __builtin_amdgcn_global_load_lds(
        (const __attribute__((address_space(1))) u32*)g,
        (__attribute__((address_space(3))) u32*)l, 16, 0, 0);
}

// ---------------------------------------------------------------------------
// Kernel 1: prep — unchanged.
// ---------------------------------------------------------------------------
__global__ __launch_bounds__(256) void prep_kernel(
    const float* __restrict__ q, const float* __restrict__ p,
    const float* __restrict__ L,
    bf16_t* __restrict__ lqb, bf16_t* __restrict__ pb,
    uint64_t* __restrict__ Lb,
    float* __restrict__ e, float* __restrict__ kld,
    float* __restrict__ CS, float* __restrict__ CL, float* __restrict__ EL,
    int* __restrict__ done)
{
    const int row = blockIdx.x;
    const int t   = threadIdx.x;
    const int wv  = t >> 6, ln = t & 63;

    const float4* q4 = (const float4*)(q + (size_t)row * DDIM);
    const float4* p4 = (const float4*)(p + (size_t)row * DDIM);
    float4 qv = q4[t];
    float4 pv = p4[t];

    float lq0 = __logf(qv.x), lq1 = __logf(qv.y), lq2 = __logf(qv.z), lq3 = __logf(qv.w);
    float lp0 = __logf(pv.x), lp1 = __logf(pv.y), lp2 = __logf(pv.z), lp3 = __logf(pv.w);

    float esum = pv.x * lp0 + pv.y * lp1 + pv.z * lp2 + pv.w * lp3;
    float ksum = pv.x * (lp0 - lq0) + pv.y * (lp1 - lq1)
               + pv.z * (lp2 - lq2) + pv.w * (lp3 - lq3);

    ushort4 uq, up;
    uq.x = f2bf_bits(lq0); uq.y = f2bf_bits(lq1); uq.z = f2bf_bits(lq2); uq.w = f2bf_bits(lq3);
    up.x = f2bf_bits(pv.x); up.y = f2bf_bits(pv.y); up.z = f2bf_bits(pv.z); up.w = f2bf_bits(pv.w);
    ((ushort4*)(lqb + (size_t)row * DDIM))[t] = uq;
    ((ushort4*)(pb  + (size_t)row * DDIM))[t] = up;

    const float4* L4 = (const float4*)(L + (size_t)row * BROWS);
    #pragma unroll
    for (int s = 0; s < 4; s++) {
        float4 lv = L4[s * 256 + t];
        unsigned long long b0 = __ballot(lv.x != 0.0f);
        unsigned long long b1 = __ballot(lv.y != 0.0f);
        unsigned long long b2 = __ballot(lv.z != 0.0f);
        unsigned long long b3 = __ballot(lv.w != 0.0f);
        if (ln < 4) {
            unsigned long long w = (ln == 0) ? b0 : (ln == 1) ? b1 : (ln == 2) ? b2 : b3;
            Lb[(size_t)row * 64 + (s * 4 + wv) * 4 + ln] = w;
        }
    }

    if (t == 0) { CS[row] = 0.f; CL[row] = 0.f; EL[row] = 0.f; }
    if (row == 0 && t == 0) *done = 0;

    #pragma unroll
    for (int off = 32; off > 0; off >>= 1) {
        esum += __shfl_down(esum, off);
        ksum += __shfl_down(ksum, off);
    }
    __shared__ float se[4], sk[4];
    if (ln == 0) { se[wv] = esum; sk[wv] = ksum; }
    __syncthreads();
    if (t == 0) {
        e[row]   = se[0] + se[1] + se[2] + se[3];
        kld[row] = (sk[0] + sk[1] + sk[2] + sk[3]) * (1.0f / DDIM);
    }
}

// ---------------------------------------------------------------------------
// Kernel 2: 128x128 GEMM, T3-minimum 2-phase (m230/m99-class):
//   double-buffered gload_lds, stage-issued-early, ONE vmcnt(0)+barrier per
//   K-step; 64KB LDS -> 2 blocks/CU for cross-block overlap (m114).
//   Involution swizzle: LDS[row][slot] holds global col (slot^(row&7));
//   readers XOR their slot with (row&7). Conflict-free, verified R1/R2.
// ---------------------------------------------------------------------------
__global__ __launch_bounds__(256, 2) void gemm_epi_kernel(
    const bf16_t* __restrict__ Abf,   // log_q [B,D]
    const bf16_t* __restrict__ Bbf,   // p     [B,D]
    const uint64_t* __restrict__ Lb,  // [B,64] ballot-native bitmask
    const float*  __restrict__ e,     // [B]
    const float*  __restrict__ kld,   // [B]
    float* __restrict__ CS, float* __restrict__ CL, float* __restrict__ EL,
    int* __restrict__ done, float* __restrict__ out)
{
    __shared__ __align__(16) bf16_t As[2 * 128 * 64];   // 32 KB (2 x 16 KB)
    __shared__ __align__(16) bf16_t Bs[2 * 128 * 64];   // 32 KB

    const int t     = threadIdx.x;     // 0..255
    const int b     = blockIdx.x;
    // bijective XCD-chunked swizzle: 1024 blocks = 32x32 tiles, 128 tiles/XCD
    const int xcd   = b & 7;
    const int s     = b >> 3;                       // 0..127
    const int i_idx = (xcd >> 2) * 16 + (s >> 3);   // 0..31
    const int j_idx = (xcd & 3) * 8 + (s & 7);      // 0..31
    const int i0    = i_idx * 128;
    const int j0    = j_idx * 128;
    const int wave  = t >> 6;          // 0..3
    const int lane  = t & 63;
    const int q4u   = lane >> 4;
    const int ln    = lane & 15;
    const int wr    = wave & 1;        // 2x2 waves, 64x64 output each
    const int wc    = wave >> 1;

    f32x4 acc[4][4];
    #pragma unroll
    for (int a = 0; a < 4; a++)
        #pragma unroll
        for (int bq = 0; bq < 4; bq++)
            acc[a][bq] = (f32x4){0.f, 0.f, 0.f, 0.f};

    // staging: thread covers (row = id>>3, 16B slot = id&7) of [128][64];
    // LDS dest LINEAR (id*16 B, wave-uniform base + lane*16 as HW requires);
    // global source slot pre-XOR'd with (row&7) (involution).
    const bf16_t* gA[4]; const bf16_t* gB[4]; int ld[4];
    #pragma unroll
    for (int n = 0; n < 4; n++) {
        const int id    = t + n * 256;
        const int row   = id >> 3;
        const int sslot = (id & 7) ^ (row & 7);
        gA[n] = Abf + (size_t)(i0 + row) * DDIM + sslot * 8;
        gB[n] = Bbf + (size_t)(j0 + row) * DDIM + sslot * 8;
        ld[n] = id * 16;
    }

    // read-side byte offsets: row stride 128B; slot = (kh*4+q4) ^ (ln&7)
    const int arow = (wr * 64 + ln) * 128;
    const int brow = (wc * 64 + ln) * 128;
    const int c0   = ((q4u    ) ^ (ln & 7)) * 16;   // kh = 0
    const int c1   = ((4 + q4u) ^ (ln & 7)) * 16;   // kh = 1

    // prologue: stage K-tile 0 into buffer 0, drain, barrier
    #pragma unroll
    for (int n = 0; n < 4; n++) gload16(gA[n], (char*)As + ld[n]);
    #pragma unroll
    for (int n = 0; n < 4; n++) gload16(gB[n], (char*)Bs + ld[n]);
    __asm__ volatile("s_waitcnt vmcnt(0)" ::: "memory");
    __builtin_amdgcn_s_barrier();

    #pragma unroll 1
    for (int it = 0; it < NKT; ++it) {
        const int cur = it & 1;
        const char* Ab = (const char*)As + cur * 16384;
        const char* Bb = (const char*)Bs + cur * 16384;

        // stage NEXT tile first (latency hides under this tile's compute)
        if (it + 1 < NKT) {
            const int k  = (it + 1) * 64;
            const int nb = (cur ^ 1) * 16384;
            #pragma unroll
            for (int n = 0; n < 4; n++) gload16(gA[n] + k, (char*)As + nb + ld[n]);
            #pragma unroll
            for (int n = 0; n < 4; n++) gload16(gB[n] + k, (char*)Bs + nb + ld[n]);
        }

        bf16x8 a0[4], b0[4], a1[4], b1[4];
        #pragma unroll
        for (int f = 0; f < 4; f++) a0[f] = *(const bf16x8*)(Ab + arow + f * 2048 + c0);
        #pragma unroll
        for (int f = 0; f < 4; f++) b0[f] = *(const bf16x8*)(Bb + brow + f * 2048 + c0);
        #pragma unroll
        for (int f = 0; f < 4; f++) a1[f] = *(const bf16x8*)(Ab + arow + f * 2048 + c1);
        #pragma unroll
        for (int f = 0; f < 4; f++) b1[f] = *(const bf16x8*)(Bb + brow + f * 2048 + c1);

        #pragma unroll
        for (int mi = 0; mi < 4; mi++)
            #pragma unroll
            for (int ni = 0; ni < 4; ni++)
                acc[mi][ni] = __builtin_amdgcn_mfma_f32_16x16x32_bf16(
                    a0[mi], b0[ni], acc[mi][ni], 0, 0, 0);
        #pragma unroll
        for (int mi = 0; mi < 4; mi++)
            #pragma unroll
            for (int ni = 0; ni < 4; ni++)
                acc[mi][ni] = __builtin_amdgcn_mfma_f32_16x16x32_bf16(
                    a1[mi], b1[ni], acc[mi][ni], 0, 0, 0);

        // single counted drain + barrier per K-step (next buffer resident)
        if (it + 1 < NKT) {
            __asm__ volatile("s_waitcnt vmcnt(0)" ::: "memory");
        }
        __asm__ volatile("" ::: "memory");
        __builtin_amdgcn_s_barrier();
    }

    // ---- epilogue: C/D col = lane&15 (=j), row = quad*4+reg (=i) ----
    const int i_base = i0 + wr * 64;
    const int j_base = j0 + wc * 64;
    const int wbase  = (j_base >> 8) * 4 + (ln & 3);
    const int bshift = ((j_base & 255) >> 2) + (ln >> 2);

    float e_j[4];
    #pragma unroll
    for (int ni = 0; ni < 4; ni++) e_j[ni] = e[j_base + ni * 16 + ln];

    #pragma unroll
    for (int mi = 0; mi < 4; mi++) {
        #pragma unroll
        for (int r = 0; r < 4; r++) {
            const int i = i_base + mi * 16 + q4u * 4 + r;
            const uint64_t m  = Lb[(size_t)i * 64 + wbase];
            const uint64_t ms = m >> bshift;
            float cs = 0.f, cl = 0.f, el = 0.f;
            #pragma unroll
            for (int ni = 0; ni < 4; ni++) {
                float cv = acc[mi][ni][r];
                cs += cv;
                if ((ms >> (ni * 4)) & 1ull) { cl += cv; el += e_j[ni]; }
            }
            #pragma unroll
            for (int sft = 1; sft < 16; sft <<= 1) {
                cs += __shfl_xor(cs, sft);
                cl += __shfl_xor(cl, sft);
                el += __shfl_xor(el, sft);
            }
            if (ln == 0) {
                atomicAdd(&CS[i], cs);
                atomicAdd(&CL[i], cl);
                atomicAdd(&EL[i], el);
            }
        }
    }

    // ---- fused final: device-scope atomics are the coherent point ----
    __asm__ volatile("s_waitcnt vmcnt(0)" ::: "memory");
    __syncthreads();
    __shared__ int sIsLast;
    if (t == 0) sIsLast = (atomicAdd(done, 1) == GEMM_BLOCKS - 1) ? 1 : 0;
    __syncthreads();
    if (sIsLast) {
        __shared__ float sred[4];
        __shared__ float sEtot;
        const int wv = t >> 6;

        float ssum = 0.f;
        #pragma unroll
        for (int j = t; j < BROWS; j += 256) ssum += e[j];
        #pragma unroll
        for (int off = 32; off > 0; off >>= 1) ssum += __shfl_down(ssum, off);
        if (lane == 0) sred[wv] = ssum;
        __syncthreads();
        if (t == 0) {
            float a = 0.f;
            #pragma unroll
            for (int k = 0; k < 4; k++) a += sred[k];
            sEtot = a;
        }
        __syncthreads();
        const float Etot = sEtot;
        const float invD = 1.0f / DDIM;

        float rs = 0.f;
        #pragma unroll
        for (int i = t; i < BROWS; i += 256) {
            float el = __hip_atomic_load(&EL[i], __ATOMIC_RELAXED, __HIP_MEMORY_SCOPE_AGENT);
            float cl = __hip_atomic_load(&CL[i], __ATOMIC_RELAXED, __HIP_MEMORY_SCOPE_AGENT);
            float cs = __hip_atomic_load(&CS[i], __ATOMIC_RELAXED, __HIP_MEMORY_SCOPE_AGENT);
            float pos = kld[i] + (el - cl) * invD;
            float neg = (Etot - el - cs + cl) * invD;
            rs += pos / neg;
        }
        __syncthreads();
        #pragma unroll
        for (int off = 32; off > 0; off >>= 1) rs += __shfl_down(rs, off);
        if (lane == 0) sred[wv] = rs;
        __syncthreads();
        if (t == 0) {
            float a = 0.f;
            #pragma unroll
            for (int k = 0; k < 4; k++) a += sred[k];
            out[0] = a;
        }
    }
}

// ---------------------------------------------------------------------------
extern "C" void kernel_launch(void* const* d_in, const int* in_sizes, int n_in,
                              void* d_out, int out_size, void* d_ws, size_t ws_size,
                              hipStream_t stream)
{
    const float* q = (const float*)d_in[0];
    const float* p = (const float*)d_in[1];
    const float* L = (const float*)d_in[2];
    float* out = (float*)d_out;

    char* ws = (char*)d_ws;
    bf16_t* lqb = (bf16_t*)ws;                                    // 8 MB
    bf16_t* pb  = (bf16_t*)(ws + (size_t)BROWS * DDIM * 2);       // 8 MB
    float*  e   = (float*)(ws + (size_t)BROWS * DDIM * 4);        // 16 KB
    float*  kld = e + BROWS;
    float*  CS  = kld + BROWS;
    float*  CL  = CS + BROWS;
    float*  EL  = CL + BROWS;
    uint64_t* Lb = (uint64_t*)(EL + BROWS);                       // 2 MB
    int*    done = (int*)(Lb + (size_t)BROWS * 64);

    prep_kernel<<<BROWS, 256, 0, stream>>>(q, p, L, lqb, pb, Lb, e, kld, CS, CL, EL, done);

    gemm_epi_kernel<<<GEMM_BLOCKS, 256, 0, stream>>>(lqb, pb, Lb, e, kld,
                                                     CS, CL, EL, done, out);
}